// Round 3
// baseline (667.974 us; speedup 1.0000x reference)
//
#include <hip/hip_runtime.h>
#include <stdint.h>

#define NN 100000
#define EE 1600000
#define DD 64
#define NB 391   // ceil(NN/256)

// ---------------- CSR build via linked lists (no random scatter stores) ----------------

__global__ void build_kernel(const int* __restrict__ dst,
                             int* __restrict__ cnt, int* __restrict__ head,
                             int* __restrict__ next) {
    int e = blockIdx.x * blockDim.x + threadIdx.x;
    if (e < EE) {
        int d = dst[e];
        atomicAdd(&cnt[d], 1);
        next[e] = atomicExch(&head[d], e);   // coalesced store, random atomic
    }
}

__global__ void scan1(const int* __restrict__ cnt, int* __restrict__ partial) {
    __shared__ int s[256];
    int i = blockIdx.x * 256 + threadIdx.x;
    int v = (i < NN) ? cnt[i] : 0;
    s[threadIdx.x] = v;
    __syncthreads();
    for (int off = 128; off > 0; off >>= 1) {
        if (threadIdx.x < off) s[threadIdx.x] += s[threadIdx.x + off];
        __syncthreads();
    }
    if (threadIdx.x == 0) partial[blockIdx.x] = s[0];
}

__global__ void scan2(int* __restrict__ partial) {
    __shared__ int s[512];
    int t = threadIdx.x;
    int v = (t < NB) ? partial[t] : 0;
    s[t] = v;
    __syncthreads();
    for (int off = 1; off < 512; off <<= 1) {
        int add = (t >= off) ? s[t - off] : 0;
        __syncthreads();
        s[t] += add;
        __syncthreads();
    }
    if (t < NB) partial[t] = s[t] - v;  // exclusive
}

__global__ void scan3(const int* __restrict__ cnt, const int* __restrict__ partial,
                      int* __restrict__ offsets) {
    __shared__ int s[256];
    int t = threadIdx.x;
    int i = blockIdx.x * 256 + t;
    int v = (i < NN) ? cnt[i] : 0;
    s[t] = v;
    __syncthreads();
    for (int off = 1; off < 256; off <<= 1) {
        int add = (t >= off) ? s[t - off] : 0;
        __syncthreads();
        s[t] += add;
        __syncthreads();
    }
    int excl = s[t] - v + partial[blockIdx.x];
    if (i < NN) {
        offsets[i] = excl;
        if (i == NN - 1) offsets[NN] = excl + v;
    }
}

// 1 thread per node: walk linked list, write csr contiguously (full-line writes)
__global__ void walk_kernel(const int* __restrict__ head, const int* __restrict__ next,
                            const int* __restrict__ srcA, const int* __restrict__ offsets,
                            int* __restrict__ csr) {
    int i = blockIdx.x * 256 + threadIdx.x;
    if (i >= NN) return;
    int p = head[i];
    int w = offsets[i];
    while (p >= 0) {
        csr[w++] = srcA[p];
        p = next[p];
    }
}

// ---------------- fused 3-way GEMM: Xl = h@Wl+bl (gather target), XRS = [h@Wr+br | h@Ws+bs] ----------------

__global__ __launch_bounds__(256) void gemm_fused(
    const float* __restrict__ hin,
    const float* __restrict__ Wl, const float* __restrict__ Wr, const float* __restrict__ Ws,
    const float* __restrict__ bl, const float* __restrict__ br, const float* __restrict__ bs,
    float* __restrict__ Xl, float* __restrict__ XRS) {
    __shared__ float Wlds[64][192];
    __shared__ float bias[192];
    __shared__ float ht[32][64];
    int t = threadIdx.x;
    for (int idx = t; idx < 64 * 64; idx += 256) {
        int k = idx >> 6, c = idx & 63;
        Wlds[k][c]        = Wl[idx];
        Wlds[k][64 + c]   = Wr[idx];
        Wlds[k][128 + c]  = Ws[idx];
    }
    if (t < 64) { bias[t] = bl[t]; bias[64 + t] = br[t]; bias[128 + t] = bs[t]; }
    int row0 = blockIdx.x * 32;
    for (int idx = t; idx < 32 * 64; idx += 256) {
        ht[idx >> 6][idx & 63] = hin[(size_t)(row0 + (idx >> 6)) * 64 + (idx & 63)];
    }
    __syncthreads();

    int c  = t & 63;
    int rg = t >> 6;  // 0..3 -> rows rg*8 .. rg*8+7
    float acc0[8], acc1[8], acc2[8];
#pragma unroll
    for (int r = 0; r < 8; r++) { acc0[r] = 0.f; acc1[r] = 0.f; acc2[r] = 0.f; }
#pragma unroll 2
    for (int k0 = 0; k0 < 64; k0 += 4) {
        float w0[4], w1[4], w2[4];
#pragma unroll
        for (int kk = 0; kk < 4; kk++) {
            w0[kk] = Wlds[k0 + kk][c];
            w1[kk] = Wlds[k0 + kk][64 + c];
            w2[kk] = Wlds[k0 + kk][128 + c];
        }
#pragma unroll
        for (int rr = 0; rr < 8; rr++) {
            float4 hv = *(const float4*)&ht[rg * 8 + rr][k0];  // broadcast b128
            acc0[rr] += hv.x * w0[0] + hv.y * w0[1] + hv.z * w0[2] + hv.w * w0[3];
            acc1[rr] += hv.x * w1[0] + hv.y * w1[1] + hv.z * w1[2] + hv.w * w1[3];
            acc2[rr] += hv.x * w2[0] + hv.y * w2[1] + hv.z * w2[2] + hv.w * w2[3];
        }
    }
    float b0 = bias[c], b1 = bias[64 + c], b2 = bias[128 + c];
#pragma unroll
    for (int rr = 0; rr < 8; rr++) {
        size_t row = row0 + rg * 8 + rr;
        Xl[row * 64 + c]        = acc0[rr] + b0;
        XRS[row * 128 + c]      = acc1[rr] + b1;
        XRS[row * 128 + 64 + c] = acc2[rr] + b2;
    }
}

// ---------------- per-node attention aggregation (one wave per dst node) ----------------

// Full-wave sum-reduce, all lanes get the total.
// xor1,xor2 via DPP quad_perm; xor4,xor8 via row_half_mirror/row_mirror (valid because
// quads are uniform after xor1+xor2, so mirror == xor); xor16 via ds_swizzle; xor32 via shfl.
__device__ __forceinline__ float wave_sum64(float t) {
    t += __int_as_float(__builtin_amdgcn_update_dpp(0, __float_as_int(t), 0xB1, 0xF, 0xF, true));   // xor1
    t += __int_as_float(__builtin_amdgcn_update_dpp(0, __float_as_int(t), 0x4E, 0xF, 0xF, true));   // xor2
    t += __int_as_float(__builtin_amdgcn_update_dpp(0, __float_as_int(t), 0x141, 0xF, 0xF, true));  // row_half_mirror ~ xor4
    t += __int_as_float(__builtin_amdgcn_update_dpp(0, __float_as_int(t), 0x140, 0xF, 0xF, true));  // row_mirror ~ xor8
    t += __int_as_float(__builtin_amdgcn_ds_swizzle(__float_as_int(t), 0x401F));                    // xor16
    t += __shfl_xor(t, 32, 64);                                                                     // xor32
    return t;
}

__device__ __forceinline__ float lrelu(float v) {
    return (v > 0.f) ? v : 0.2f * v;
}

__global__ __launch_bounds__(256) void node_kernel(
    const float* __restrict__ Xl, const float* __restrict__ XRS,
    const int* __restrict__ offsets, const int* __restrict__ csr,
    const float* __restrict__ att, const float* __restrict__ bg,
    float* __restrict__ hout, int do_relu) {
    int lane = threadIdx.x & 63;
    int wid  = threadIdx.x >> 6;
    int i = blockIdx.x * 4 + wid;
    if (i >= NN) return;
    float xr   = XRS[(size_t)i * 128 + lane];
    float attk = att[lane];
    float agg = 0.f, denom = 0.f;
    int beg = offsets[i], end = offsets[i + 1];
    int j = beg;
    // 4-wide unroll: 4 independent gather+reduce chains in flight
    for (; j + 4 <= end; j += 4) {
        int s0 = csr[j], s1 = csr[j + 1], s2 = csr[j + 2], s3 = csr[j + 3];
        float x0 = Xl[(size_t)s0 * 64 + lane];
        float x1 = Xl[(size_t)s1 * 64 + lane];
        float x2 = Xl[(size_t)s2 * 64 + lane];
        float x3 = Xl[(size_t)s3 * 64 + lane];
        float t0 = lrelu(x0 + xr) * attk;
        float t1 = lrelu(x1 + xr) * attk;
        float t2 = lrelu(x2 + xr) * attk;
        float t3 = lrelu(x3 + xr) * attk;
        t0 = wave_sum64(t0);
        t1 = wave_sum64(t1);
        t2 = wave_sum64(t2);
        t3 = wave_sum64(t3);
        float a0 = __expf(t0), a1 = __expf(t1), a2 = __expf(t2), a3 = __expf(t3);
        agg += a0 * x0 + a1 * x1 + a2 * x2 + a3 * x3;
        denom += (a0 + a1) + (a2 + a3);
    }
    for (; j < end; j++) {
        int s = csr[j];
        float xls = Xl[(size_t)s * 64 + lane];
        float tsum = wave_sum64(lrelu(xls + xr) * attk);
        float a = __expf(tsum);
        agg   += a * xls;
        denom += a;
    }
    float inv = (denom > 0.f) ? (1.0f / denom) : 0.f;
    float res = agg * inv + bg[lane] + XRS[(size_t)i * 128 + 64 + lane];
    if (do_relu) res = (res > 0.f) ? res : 0.f;
    hout[(size_t)i * 64 + lane] = res;
}

// ---------------- final projection out = h @ Wout + bout ----------------

__global__ __launch_bounds__(256) void out_kernel(
    const float* __restrict__ h, const float* __restrict__ Wout,
    const float* __restrict__ bout, float* __restrict__ out) {
    int lane = threadIdx.x & 63;
    int wid  = threadIdx.x >> 6;
    int i = blockIdx.x * 4 + wid;
    if (i >= NN) return;
    float p  = h[(size_t)i * 64 + lane];
    float a0 = p * Wout[lane * 2 + 0];
    float a1 = p * Wout[lane * 2 + 1];
#pragma unroll
    for (int m = 1; m < 64; m <<= 1) {
        a0 += __shfl_xor(a0, m, 64);
        a1 += __shfl_xor(a1, m, 64);
    }
    if (lane == 0) {
        out[(size_t)i * 2 + 0] = a0 + bout[0];
        out[(size_t)i * 2 + 1] = a1 + bout[1];
    }
}

// ---------------- launch ----------------

extern "C" void kernel_launch(void* const* d_in, const int* in_sizes, int n_in,
                              void* d_out, int out_size, void* d_ws, size_t ws_size,
                              hipStream_t stream) {
    const float* x    = (const float*)d_in[0];
    const int*   ei   = (const int*)d_in[1];   // [2][E]: row0=src, row1=dst
    const float* Wl   = (const float*)d_in[2];
    const float* bl   = (const float*)d_in[3];
    const float* Wr   = (const float*)d_in[4];
    const float* br   = (const float*)d_in[5];
    const float* att  = (const float*)d_in[6];
    const float* bg   = (const float*)d_in[7];
    const float* Ws   = (const float*)d_in[8];
    const float* bs   = (const float*)d_in[9];
    const float* Wout = (const float*)d_in[10];
    const float* bout = (const float*)d_in[11];
    float* out = (float*)d_out;

    size_t off = 0;
    char* base = (char*)d_ws;
    auto alloc = [&](size_t bytes) -> void* {
        void* p = base + off;
        off += (bytes + 255) & ~(size_t)255;
        return p;
    };
    float* Xl     = (float*)alloc((size_t)NN * 64 * 4);
    float* XRS    = (float*)alloc((size_t)NN * 128 * 4);
    float* h      = (float*)alloc((size_t)NN * 64 * 4);
    int*   cnt    = (int*)alloc((size_t)NN * 4);
    int*   headA  = (int*)alloc((size_t)NN * 4);
    int*   nextA  = (int*)alloc((size_t)EE * 4);
    int*   offs   = (int*)alloc((size_t)(NN + 1) * 4);
    int*   csr    = (int*)alloc((size_t)EE * 4);
    int*   part   = (int*)alloc(512 * 4);

    const int* src = ei;
    const int* dst = ei + EE;

    hipMemsetAsync(cnt, 0, (size_t)NN * 4, stream);
    hipMemsetAsync(headA, 0xFF, (size_t)NN * 4, stream);   // -1
    build_kernel<<<(EE + 255) / 256, 256, 0, stream>>>(dst, cnt, headA, nextA);
    scan1<<<NB, 256, 0, stream>>>(cnt, part);
    scan2<<<1, 512, 0, stream>>>(part);
    scan3<<<NB, 256, 0, stream>>>(cnt, part, offs);
    walk_kernel<<<NB, 256, 0, stream>>>(headA, nextA, src, offs, csr);

    const float* hin = x;
    for (int L = 0; L < 3; L++) {
        gemm_fused<<<NN / 32, 256, 0, stream>>>(
            hin, Wl + L * 4096, Wr + L * 4096, Ws + L * 4096,
            bl + L * 64, br + L * 64, bs + L * 64, Xl, XRS);
        node_kernel<<<NN / 4, 256, 0, stream>>>(
            Xl, XRS, offs, csr, att + L * 64, bg + L * 64, h, (L < 2) ? 1 : 0);
        hin = h;
    }
    out_kernel<<<NN / 4, 256, 0, stream>>>(h, Wout, bout, out);
}

// Round 4
// 603.290 us; speedup vs baseline: 1.1072x; 1.1072x over previous
//
#include <hip/hip_runtime.h>
#include <stdint.h>

#define NN 100000
#define EE 1600000
#define DD 64
#define NB 391   // ceil(NN/256)

// ---------------- CSR build via linked lists (single atomic per edge) ----------------

__global__ void build_kernel(const int* __restrict__ dst,
                             int* __restrict__ head, int* __restrict__ next) {
    int e = blockIdx.x * blockDim.x + threadIdx.x;
    if (e < EE) {
        next[e] = atomicExch(&head[dst[e]], e);   // only atomic in the build
    }
}

// 1 thread/node: chain length -> cnt (no atomics)
__global__ void count_walk(const int* __restrict__ head, const int* __restrict__ next,
                           int* __restrict__ cnt) {
    int i = blockIdx.x * 256 + threadIdx.x;
    if (i >= NN) return;
    int c = 0;
    for (int p = head[i]; p >= 0; p = next[p]) c++;
    cnt[i] = c;
}

__global__ void scan1(const int* __restrict__ cnt, int* __restrict__ partial) {
    __shared__ int s[256];
    int i = blockIdx.x * 256 + threadIdx.x;
    int v = (i < NN) ? cnt[i] : 0;
    s[threadIdx.x] = v;
    __syncthreads();
    for (int off = 128; off > 0; off >>= 1) {
        if (threadIdx.x < off) s[threadIdx.x] += s[threadIdx.x + off];
        __syncthreads();
    }
    if (threadIdx.x == 0) partial[blockIdx.x] = s[0];
}

__global__ void scan2(int* __restrict__ partial) {
    __shared__ int s[512];
    int t = threadIdx.x;
    int v = (t < NB) ? partial[t] : 0;
    s[t] = v;
    __syncthreads();
    for (int off = 1; off < 512; off <<= 1) {
        int add = (t >= off) ? s[t - off] : 0;
        __syncthreads();
        s[t] += add;
        __syncthreads();
    }
    if (t < NB) partial[t] = s[t] - v;  // exclusive
}

__global__ void scan3(const int* __restrict__ cnt, const int* __restrict__ partial,
                      int* __restrict__ offsets) {
    __shared__ int s[256];
    int t = threadIdx.x;
    int i = blockIdx.x * 256 + t;
    int v = (i < NN) ? cnt[i] : 0;
    s[t] = v;
    __syncthreads();
    for (int off = 1; off < 256; off <<= 1) {
        int add = (t >= off) ? s[t - off] : 0;
        __syncthreads();
        s[t] += add;
        __syncthreads();
    }
    int excl = s[t] - v + partial[blockIdx.x];
    if (i < NN) {
        offsets[i] = excl;
        if (i == NN - 1) offsets[NN] = excl + v;
    }
}

// 1 thread per node: walk linked list, write csr contiguously (full-line writes)
__global__ void walk_kernel(const int* __restrict__ head, const int* __restrict__ next,
                            const int* __restrict__ srcA, const int* __restrict__ offsets,
                            int* __restrict__ csr) {
    int i = blockIdx.x * 256 + threadIdx.x;
    if (i >= NN) return;
    int p = head[i];
    int w = offsets[i];
    while (p >= 0) {
        csr[w++] = srcA[p];
        p = next[p];
    }
}

// ---------------- fused 3-way GEMM: Xl = h@Wl+bl (gather target), XRS = [h@Wr+br | h@Ws+bs] ----------------

__global__ __launch_bounds__(256) void gemm_fused(
    const float* __restrict__ hin,
    const float* __restrict__ Wl, const float* __restrict__ Wr, const float* __restrict__ Ws,
    const float* __restrict__ bl, const float* __restrict__ br, const float* __restrict__ bs,
    float* __restrict__ Xl, float* __restrict__ XRS) {
    __shared__ float Wlds[64][192];
    __shared__ float bias[192];
    __shared__ float ht[32][64];
    int t = threadIdx.x;
    for (int idx = t; idx < 64 * 64; idx += 256) {
        int k = idx >> 6, c = idx & 63;
        Wlds[k][c]        = Wl[idx];
        Wlds[k][64 + c]   = Wr[idx];
        Wlds[k][128 + c]  = Ws[idx];
    }
    if (t < 64) { bias[t] = bl[t]; bias[64 + t] = br[t]; bias[128 + t] = bs[t]; }
    int row0 = blockIdx.x * 32;
    for (int idx = t; idx < 32 * 64; idx += 256) {
        ht[idx >> 6][idx & 63] = hin[(size_t)(row0 + (idx >> 6)) * 64 + (idx & 63)];
    }
    __syncthreads();

    int c  = t & 63;
    int rg = t >> 6;  // 0..3 -> rows rg*8 .. rg*8+7
    float acc0[8], acc1[8], acc2[8];
#pragma unroll
    for (int r = 0; r < 8; r++) { acc0[r] = 0.f; acc1[r] = 0.f; acc2[r] = 0.f; }
#pragma unroll 2
    for (int k0 = 0; k0 < 64; k0 += 4) {
        float w0[4], w1[4], w2[4];
#pragma unroll
        for (int kk = 0; kk < 4; kk++) {
            w0[kk] = Wlds[k0 + kk][c];
            w1[kk] = Wlds[k0 + kk][64 + c];
            w2[kk] = Wlds[k0 + kk][128 + c];
        }
#pragma unroll
        for (int rr = 0; rr < 8; rr++) {
            float4 hv = *(const float4*)&ht[rg * 8 + rr][k0];  // broadcast b128
            acc0[rr] += hv.x * w0[0] + hv.y * w0[1] + hv.z * w0[2] + hv.w * w0[3];
            acc1[rr] += hv.x * w1[0] + hv.y * w1[1] + hv.z * w1[2] + hv.w * w1[3];
            acc2[rr] += hv.x * w2[0] + hv.y * w2[1] + hv.z * w2[2] + hv.w * w2[3];
        }
    }
    float b0 = bias[c], b1 = bias[64 + c], b2 = bias[128 + c];
#pragma unroll
    for (int rr = 0; rr < 8; rr++) {
        size_t row = row0 + rg * 8 + rr;
        Xl[row * 64 + c]        = acc0[rr] + b0;
        XRS[row * 128 + c]      = acc1[rr] + b1;
        XRS[row * 128 + 64 + c] = acc2[rr] + b2;
    }
}

// ---------------- per-node attention aggregation (one wave per dst node) ----------------

__device__ __forceinline__ float wave_sum64(float t) {
    t += __int_as_float(__builtin_amdgcn_update_dpp(0, __float_as_int(t), 0xB1, 0xF, 0xF, true));   // xor1
    t += __int_as_float(__builtin_amdgcn_update_dpp(0, __float_as_int(t), 0x4E, 0xF, 0xF, true));   // xor2
    t += __int_as_float(__builtin_amdgcn_update_dpp(0, __float_as_int(t), 0x141, 0xF, 0xF, true));  // row_half_mirror ~ xor4
    t += __int_as_float(__builtin_amdgcn_update_dpp(0, __float_as_int(t), 0x140, 0xF, 0xF, true));  // row_mirror ~ xor8
    t += __int_as_float(__builtin_amdgcn_ds_swizzle(__float_as_int(t), 0x401F));                    // xor16
    t += __shfl_xor(t, 32, 64);                                                                     // xor32
    return t;
}

__device__ __forceinline__ float lrelu(float v) {
    return (v > 0.f) ? v : 0.2f * v;
}

__global__ __launch_bounds__(256) void node_kernel(
    const float* __restrict__ Xl, const float* __restrict__ XRS,
    const int* __restrict__ offsets, const int* __restrict__ csr,
    const float* __restrict__ att, const float* __restrict__ bg,
    float* __restrict__ hout, int do_relu) {
    int lane = threadIdx.x & 63;
    int wid  = threadIdx.x >> 6;
    int i = blockIdx.x * 4 + wid;
    if (i >= NN) return;
    float xr   = XRS[(size_t)i * 128 + lane];
    float attk = att[lane];
    float agg = 0.f, denom = 0.f;
    int beg = offsets[i], end = offsets[i + 1];
    int j = beg;
    for (; j + 4 <= end; j += 4) {
        int s0 = csr[j], s1 = csr[j + 1], s2 = csr[j + 2], s3 = csr[j + 3];
        float x0 = Xl[(size_t)s0 * 64 + lane];
        float x1 = Xl[(size_t)s1 * 64 + lane];
        float x2 = Xl[(size_t)s2 * 64 + lane];
        float x3 = Xl[(size_t)s3 * 64 + lane];
        float t0 = lrelu(x0 + xr) * attk;
        float t1 = lrelu(x1 + xr) * attk;
        float t2 = lrelu(x2 + xr) * attk;
        float t3 = lrelu(x3 + xr) * attk;
        t0 = wave_sum64(t0);
        t1 = wave_sum64(t1);
        t2 = wave_sum64(t2);
        t3 = wave_sum64(t3);
        float a0 = __expf(t0), a1 = __expf(t1), a2 = __expf(t2), a3 = __expf(t3);
        agg += a0 * x0 + a1 * x1 + a2 * x2 + a3 * x3;
        denom += (a0 + a1) + (a2 + a3);
    }
    for (; j < end; j++) {
        int s = csr[j];
        float xls = Xl[(size_t)s * 64 + lane];
        float tsum = wave_sum64(lrelu(xls + xr) * attk);
        float a = __expf(tsum);
        agg   += a * xls;
        denom += a;
    }
    float inv = (denom > 0.f) ? (1.0f / denom) : 0.f;
    float res = agg * inv + bg[lane] + XRS[(size_t)i * 128 + 64 + lane];
    if (do_relu) res = (res > 0.f) ? res : 0.f;
    hout[(size_t)i * 64 + lane] = res;
}

// ---------------- final projection out = h @ Wout + bout ----------------

__global__ __launch_bounds__(256) void out_kernel(
    const float* __restrict__ h, const float* __restrict__ Wout,
    const float* __restrict__ bout, float* __restrict__ out) {
    int lane = threadIdx.x & 63;
    int wid  = threadIdx.x >> 6;
    int i = blockIdx.x * 4 + wid;
    if (i >= NN) return;
    float p  = h[(size_t)i * 64 + lane];
    float a0 = p * Wout[lane * 2 + 0];
    float a1 = p * Wout[lane * 2 + 1];
#pragma unroll
    for (int m = 1; m < 64; m <<= 1) {
        a0 += __shfl_xor(a0, m, 64);
        a1 += __shfl_xor(a1, m, 64);
    }
    if (lane == 0) {
        out[(size_t)i * 2 + 0] = a0 + bout[0];
        out[(size_t)i * 2 + 1] = a1 + bout[1];
    }
}

// ---------------- launch ----------------

extern "C" void kernel_launch(void* const* d_in, const int* in_sizes, int n_in,
                              void* d_out, int out_size, void* d_ws, size_t ws_size,
                              hipStream_t stream) {
    const float* x    = (const float*)d_in[0];
    const int*   ei   = (const int*)d_in[1];   // [2][E]: row0=src, row1=dst
    const float* Wl   = (const float*)d_in[2];
    const float* bl   = (const float*)d_in[3];
    const float* Wr   = (const float*)d_in[4];
    const float* br   = (const float*)d_in[5];
    const float* att  = (const float*)d_in[6];
    const float* bg   = (const float*)d_in[7];
    const float* Ws   = (const float*)d_in[8];
    const float* bs   = (const float*)d_in[9];
    const float* Wout = (const float*)d_in[10];
    const float* bout = (const float*)d_in[11];
    float* out = (float*)d_out;

    size_t off = 0;
    char* base = (char*)d_ws;
    auto alloc = [&](size_t bytes) -> void* {
        void* p = base + off;
        off += (bytes + 255) & ~(size_t)255;
        return p;
    };
    float* Xl     = (float*)alloc((size_t)NN * 64 * 4);
    float* XRS    = (float*)alloc((size_t)NN * 128 * 4);
    float* h      = (float*)alloc((size_t)NN * 64 * 4);
    int*   cnt    = (int*)alloc((size_t)NN * 4);
    int*   headA  = (int*)alloc((size_t)NN * 4);
    int*   nextA  = (int*)alloc((size_t)EE * 4);
    int*   offs   = (int*)alloc((size_t)(NN + 1) * 4);
    int*   csr    = (int*)alloc((size_t)EE * 4);
    int*   part   = (int*)alloc(512 * 4);

    const int* src = ei;
    const int* dst = ei + EE;

    hipMemsetAsync(headA, 0xFF, (size_t)NN * 4, stream);   // -1
    build_kernel<<<(EE + 255) / 256, 256, 0, stream>>>(dst, headA, nextA);
    count_walk<<<NB, 256, 0, stream>>>(headA, nextA, cnt);
    scan1<<<NB, 256, 0, stream>>>(cnt, part);
    scan2<<<1, 512, 0, stream>>>(part);
    scan3<<<NB, 256, 0, stream>>>(cnt, part, offs);
    walk_kernel<<<NB, 256, 0, stream>>>(headA, nextA, src, offs, csr);

    const float* hin = x;
    for (int L = 0; L < 3; L++) {
        gemm_fused<<<NN / 32, 256, 0, stream>>>(
            hin, Wl + L * 4096, Wr + L * 4096, Ws + L * 4096,
            bl + L * 64, br + L * 64, bs + L * 64, Xl, XRS);
        node_kernel<<<NN / 4, 256, 0, stream>>>(
            Xl, XRS, offs, csr, att + L * 64, bg + L * 64, h, (L < 2) ? 1 : 0);
        hin = h;
    }
    out_kernel<<<NN / 4, 256, 0, stream>>>(h, Wout, bout, out);
}

// Round 5
// 543.081 us; speedup vs baseline: 1.2300x; 1.1109x over previous
//
#include <hip/hip_runtime.h>
#include <stdint.h>

#define NN 100000
#define EE 1600000
#define DD 64
#define NB 391   // ceil(NN/256)

// ---------------- CSR build via linked lists (single atomic per edge) ----------------

__global__ void build_kernel(const int* __restrict__ dst,
                             int* __restrict__ head, int* __restrict__ next) {
    int e = blockIdx.x * blockDim.x + threadIdx.x;
    if (e < EE) {
        next[e] = atomicExch(&head[dst[e]], e);   // only atomic in the build
    }
}

// 1 thread/node: chain length -> cnt (no atomics)
__global__ void count_walk(const int* __restrict__ head, const int* __restrict__ next,
                           int* __restrict__ cnt) {
    int i = blockIdx.x * 256 + threadIdx.x;
    if (i >= NN) return;
    int c = 0;
    for (int p = head[i]; p >= 0; p = next[p]) c++;
    cnt[i] = c;
}

__global__ void scan1(const int* __restrict__ cnt, int* __restrict__ partial) {
    __shared__ int s[256];
    int i = blockIdx.x * 256 + threadIdx.x;
    int v = (i < NN) ? cnt[i] : 0;
    s[threadIdx.x] = v;
    __syncthreads();
    for (int off = 128; off > 0; off >>= 1) {
        if (threadIdx.x < off) s[threadIdx.x] += s[threadIdx.x + off];
        __syncthreads();
    }
    if (threadIdx.x == 0) partial[blockIdx.x] = s[0];
}

__global__ void scan2(int* __restrict__ partial) {
    __shared__ int s[512];
    int t = threadIdx.x;
    int v = (t < NB) ? partial[t] : 0;
    s[t] = v;
    __syncthreads();
    for (int off = 1; off < 512; off <<= 1) {
        int add = (t >= off) ? s[t - off] : 0;
        __syncthreads();
        s[t] += add;
        __syncthreads();
    }
    if (t < NB) partial[t] = s[t] - v;  // exclusive
}

__global__ void scan3(const int* __restrict__ cnt, const int* __restrict__ partial,
                      int* __restrict__ offsets) {
    __shared__ int s[256];
    int t = threadIdx.x;
    int i = blockIdx.x * 256 + t;
    int v = (i < NN) ? cnt[i] : 0;
    s[t] = v;
    __syncthreads();
    for (int off = 1; off < 256; off <<= 1) {
        int add = (t >= off) ? s[t - off] : 0;
        __syncthreads();
        s[t] += add;
        __syncthreads();
    }
    int excl = s[t] - v + partial[blockIdx.x];
    if (i < NN) {
        offsets[i] = excl;
        if (i == NN - 1) offsets[NN] = excl + v;
    }
}

// 1 thread per node: walk linked list, write csr contiguously (full-line writes)
__global__ void walk_kernel(const int* __restrict__ head, const int* __restrict__ next,
                            const int* __restrict__ srcA, const int* __restrict__ offsets,
                            int* __restrict__ csr) {
    int i = blockIdx.x * 256 + threadIdx.x;
    if (i >= NN) return;
    int p = head[i];
    int w = offsets[i];
    while (p >= 0) {
        csr[w++] = srcA[p];
        p = next[p];
    }
}

// ---------------- fused 3-way GEMM: Xl = h@Wl+bl (gather target), XRS = [h@Wr+br | h@Ws+bs] ----------------

__global__ __launch_bounds__(256) void gemm_fused(
    const float* __restrict__ hin,
    const float* __restrict__ Wl, const float* __restrict__ Wr, const float* __restrict__ Ws,
    const float* __restrict__ bl, const float* __restrict__ br, const float* __restrict__ bs,
    float* __restrict__ Xl, float* __restrict__ XRS) {
    __shared__ float Wlds[64][192];
    __shared__ float bias[192];
    __shared__ float ht[32][64];
    int t = threadIdx.x;
    for (int idx = t; idx < 64 * 64; idx += 256) {
        int k = idx >> 6, c = idx & 63;
        Wlds[k][c]        = Wl[idx];
        Wlds[k][64 + c]   = Wr[idx];
        Wlds[k][128 + c]  = Ws[idx];
    }
    if (t < 64) { bias[t] = bl[t]; bias[64 + t] = br[t]; bias[128 + t] = bs[t]; }
    int row0 = blockIdx.x * 32;
    for (int idx = t; idx < 32 * 64; idx += 256) {
        ht[idx >> 6][idx & 63] = hin[(size_t)(row0 + (idx >> 6)) * 64 + (idx & 63)];
    }
    __syncthreads();

    int c  = t & 63;
    int rg = t >> 6;  // 0..3 -> rows rg*8 .. rg*8+7
    float acc0[8], acc1[8], acc2[8];
#pragma unroll
    for (int r = 0; r < 8; r++) { acc0[r] = 0.f; acc1[r] = 0.f; acc2[r] = 0.f; }
#pragma unroll 2
    for (int k0 = 0; k0 < 64; k0 += 4) {
        float w0[4], w1[4], w2[4];
#pragma unroll
        for (int kk = 0; kk < 4; kk++) {
            w0[kk] = Wlds[k0 + kk][c];
            w1[kk] = Wlds[k0 + kk][64 + c];
            w2[kk] = Wlds[k0 + kk][128 + c];
        }
#pragma unroll
        for (int rr = 0; rr < 8; rr++) {
            float4 hv = *(const float4*)&ht[rg * 8 + rr][k0];  // broadcast b128
            acc0[rr] += hv.x * w0[0] + hv.y * w0[1] + hv.z * w0[2] + hv.w * w0[3];
            acc1[rr] += hv.x * w1[0] + hv.y * w1[1] + hv.z * w1[2] + hv.w * w1[3];
            acc2[rr] += hv.x * w2[0] + hv.y * w2[1] + hv.z * w2[2] + hv.w * w2[3];
        }
    }
    float b0 = bias[c], b1 = bias[64 + c], b2 = bias[128 + c];
#pragma unroll
    for (int rr = 0; rr < 8; rr++) {
        size_t row = row0 + rg * 8 + rr;
        Xl[row * 64 + c]        = acc0[rr] + b0;
        XRS[row * 128 + c]      = acc1[rr] + b1;
        XRS[row * 128 + 64 + c] = acc2[rr] + b2;
    }
}

// ---------------- per-node attention aggregation ----------------
// One wave per dst node; 4 edges in parallel, 16 lanes per edge.
// Lane l owns features 4*(l&15) .. 4*(l&15)+3 of its edge's xl as a float4.

// sum-reduce across a 16-lane group, all row-local DPP (no LDS pipe):
// xor1,xor2 via quad_perm; xor4 via row_half_mirror (quads uniform -> mirror==xor);
// xor8 via row_mirror (half-rows uniform -> mirror==xor).
__device__ __forceinline__ float group_sum16(float t) {
    t += __int_as_float(__builtin_amdgcn_update_dpp(0, __float_as_int(t), 0xB1, 0xF, 0xF, true));   // xor1
    t += __int_as_float(__builtin_amdgcn_update_dpp(0, __float_as_int(t), 0x4E, 0xF, 0xF, true));   // xor2
    t += __int_as_float(__builtin_amdgcn_update_dpp(0, __float_as_int(t), 0x141, 0xF, 0xF, true));  // row_half_mirror ~ xor4
    t += __int_as_float(__builtin_amdgcn_update_dpp(0, __float_as_int(t), 0x140, 0xF, 0xF, true));  // row_mirror ~ xor8
    return t;
}

__device__ __forceinline__ float lrelu(float v) {
    return (v > 0.f) ? v : 0.2f * v;
}

__global__ __launch_bounds__(256) void node_kernel(
    const float* __restrict__ Xl, const float* __restrict__ XRS,
    const int* __restrict__ offsets, const int* __restrict__ csr,
    const float* __restrict__ att, const float* __restrict__ bg,
    float* __restrict__ hout, int do_relu) {
    int lane = threadIdx.x & 63;
    int wid  = threadIdx.x >> 6;
    int i = blockIdx.x * 4 + wid;
    if (i >= NN) return;
    int sub = lane & 15;   // feature-quad index: features 4*sub..4*sub+3
    int grp = lane >> 4;   // edge slot 0..3

    float4 xr4  = *(const float4*)&XRS[(size_t)i * 128 + sub * 4];
    float4 att4 = *(const float4*)&att[sub * 4];

    float aggx = 0.f, aggy = 0.f, aggz = 0.f, aggw = 0.f;
    float denom = 0.f;
    int beg = offsets[i], end = offsets[i + 1];

    for (int j0 = beg; j0 < end; j0 += 8) {
        // two independent edge chains per lane group
        int jA = j0 + grp, jB = j0 + grp + 4;
        bool vA = jA < end, vB = jB < end;
        int sA = csr[vA ? jA : beg];
        int sB = csr[vB ? jB : beg];
        float4 xA = *(const float4*)&Xl[(size_t)sA * 64 + sub * 4];
        float4 xB = *(const float4*)&Xl[(size_t)sB * 64 + sub * 4];

        float tA = lrelu(xA.x + xr4.x) * att4.x + lrelu(xA.y + xr4.y) * att4.y
                 + lrelu(xA.z + xr4.z) * att4.z + lrelu(xA.w + xr4.w) * att4.w;
        float tB = lrelu(xB.x + xr4.x) * att4.x + lrelu(xB.y + xr4.y) * att4.y
                 + lrelu(xB.z + xr4.z) * att4.z + lrelu(xB.w + xr4.w) * att4.w;
        tA = group_sum16(tA);
        tB = group_sum16(tB);
        float aA = vA ? __expf(tA) : 0.f;
        float aB = vB ? __expf(tB) : 0.f;

        aggx += aA * xA.x + aB * xB.x;
        aggy += aA * xA.y + aB * xB.y;
        aggz += aA * xA.z + aB * xB.z;
        aggw += aA * xA.w + aB * xB.w;
        denom += aA + aB;
    }

    // combine the 4 edge groups (once per node)
#pragma unroll
    for (int m = 16; m <= 32; m <<= 1) {
        aggx  += __shfl_xor(aggx, m, 64);
        aggy  += __shfl_xor(aggy, m, 64);
        aggz  += __shfl_xor(aggz, m, 64);
        aggw  += __shfl_xor(aggw, m, 64);
        denom += __shfl_xor(denom, m, 64);
    }

    float inv = (denom > 0.f) ? (1.0f / denom) : 0.f;
    float4 sk4 = *(const float4*)&XRS[(size_t)i * 128 + 64 + sub * 4];
    float4 bg4 = *(const float4*)&bg[sub * 4];
    float4 res;
    res.x = aggx * inv + bg4.x + sk4.x;
    res.y = aggy * inv + bg4.y + sk4.y;
    res.z = aggz * inv + bg4.z + sk4.z;
    res.w = aggw * inv + bg4.w + sk4.w;
    if (do_relu) {
        res.x = fmaxf(res.x, 0.f); res.y = fmaxf(res.y, 0.f);
        res.z = fmaxf(res.z, 0.f); res.w = fmaxf(res.w, 0.f);
    }
    if (grp == 0) *(float4*)&hout[(size_t)i * 64 + sub * 4] = res;
}

// ---------------- final projection out = h @ Wout + bout ----------------

__global__ __launch_bounds__(256) void out_kernel(
    const float* __restrict__ h, const float* __restrict__ Wout,
    const float* __restrict__ bout, float* __restrict__ out) {
    int lane = threadIdx.x & 63;
    int wid  = threadIdx.x >> 6;
    int i = blockIdx.x * 4 + wid;
    if (i >= NN) return;
    float p  = h[(size_t)i * 64 + lane];
    float a0 = p * Wout[lane * 2 + 0];
    float a1 = p * Wout[lane * 2 + 1];
#pragma unroll
    for (int m = 1; m < 64; m <<= 1) {
        a0 += __shfl_xor(a0, m, 64);
        a1 += __shfl_xor(a1, m, 64);
    }
    if (lane == 0) {
        out[(size_t)i * 2 + 0] = a0 + bout[0];
        out[(size_t)i * 2 + 1] = a1 + bout[1];
    }
}

// ---------------- launch ----------------

extern "C" void kernel_launch(void* const* d_in, const int* in_sizes, int n_in,
                              void* d_out, int out_size, void* d_ws, size_t ws_size,
                              hipStream_t stream) {
    const float* x    = (const float*)d_in[0];
    const int*   ei   = (const int*)d_in[1];   // [2][E]: row0=src, row1=dst
    const float* Wl   = (const float*)d_in[2];
    const float* bl   = (const float*)d_in[3];
    const float* Wr   = (const float*)d_in[4];
    const float* br   = (const float*)d_in[5];
    const float* att  = (const float*)d_in[6];
    const float* bg   = (const float*)d_in[7];
    const float* Ws   = (const float*)d_in[8];
    const float* bs   = (const float*)d_in[9];
    const float* Wout = (const float*)d_in[10];
    const float* bout = (const float*)d_in[11];
    float* out = (float*)d_out;

    size_t off = 0;
    char* base = (char*)d_ws;
    auto alloc = [&](size_t bytes) -> void* {
        void* p = base + off;
        off += (bytes + 255) & ~(size_t)255;
        return p;
    };
    float* Xl     = (float*)alloc((size_t)NN * 64 * 4);
    float* XRS    = (float*)alloc((size_t)NN * 128 * 4);
    float* h      = (float*)alloc((size_t)NN * 64 * 4);
    int*   cnt    = (int*)alloc((size_t)NN * 4);
    int*   headA  = (int*)alloc((size_t)NN * 4);
    int*   nextA  = (int*)alloc((size_t)EE * 4);
    int*   offs   = (int*)alloc((size_t)(NN + 1) * 4);
    int*   csr    = (int*)alloc((size_t)EE * 4);
    int*   part   = (int*)alloc(512 * 4);

    const int* src = ei;
    const int* dst = ei + EE;

    hipMemsetAsync(headA, 0xFF, (size_t)NN * 4, stream);   // -1
    build_kernel<<<(EE + 255) / 256, 256, 0, stream>>>(dst, headA, nextA);
    count_walk<<<NB, 256, 0, stream>>>(headA, nextA, cnt);
    scan1<<<NB, 256, 0, stream>>>(cnt, part);
    scan2<<<1, 512, 0, stream>>>(part);
    scan3<<<NB, 256, 0, stream>>>(cnt, part, offs);
    walk_kernel<<<NB, 256, 0, stream>>>(headA, nextA, src, offs, csr);

    const float* hin = x;
    for (int L = 0; L < 3; L++) {
        gemm_fused<<<NN / 32, 256, 0, stream>>>(
            hin, Wl + L * 4096, Wr + L * 4096, Ws + L * 4096,
            bl + L * 64, br + L * 64, bs + L * 64, Xl, XRS);
        node_kernel<<<NN / 4, 256, 0, stream>>>(
            Xl, XRS, offs, csr, att + L * 64, bg + L * 64, h, (L < 2) ? 1 : 0);
        hin = h;
    }
    out_kernel<<<NN / 4, 256, 0, stream>>>(h, Wout, bout, out);
}